// Round 1
// baseline (388.220 us; speedup 1.0000x reference)
//
#include <hip/hip_runtime.h>

#define NWIN 1000
#define WIN  500
#define HID  30
#define ANC  7
#define BATCH 64
#define KS   75
#define PADH 37
#define OBASE_ELEMS (BATCH*ANC*NWIN*2)   // 896000

// ---------------------------------------------------------------------------
// Kernel 1: per-window  (x-0.5)*2 -> GEMM1 -> +b1 -> relu -> batchnorm over B
//           -> GEMM2 -> +b2 -> write out_base[b][a][n][c]
// grid = 1000 blocks (one per window), 256 threads = 4 waves.
// wave q: cbit = q>>1 (which of the 2 channels), hid half = (q&1)*15.
// lane   = batch index b (0..63)  -> batch stats are 64-lane shuffles.
// ---------------------------------------------------------------------------
__global__ __launch_bounds__(256, 2) void k1(
        const float* __restrict__ x,
        const float* __restrict__ W1, const float* __restrict__ b1,
        const float* __restrict__ W2, const float* __restrict__ b2,
        float* __restrict__ out_base)
{
    __shared__ float xs[2][64][51];   // [c][b][w_local], stride 51 (odd) -> conflict-free
    __shared__ float hsh[64][65];     // normalized h: [b][c*32 + hid], stride 65 (odd)

    const int n    = blockIdx.x;
    const int t    = threadIdx.x;
    const int q    = __builtin_amdgcn_readfirstlane(t >> 6);  // wave id, forced uniform
    const int lane = t & 63;                                   // batch index
    const int cbit  = q >> 1;
    const int hbase = (q & 1) * 15;

    const float* __restrict__ w1p = W1 + (size_t)n * (WIN * HID) + hbase;

    float acc[15];
#pragma unroll
    for (int j = 0; j < 15; ++j) acc[j] = 0.f;

    const float* xrow = &xs[cbit][lane][0];

    for (int chunk = 0; chunk < 10; ++chunk) {
        __syncthreads();
        // stage 50 w-positions for all 64 batches: 64 * 25 float4
        for (int idx = t; idx < 1600; idx += 256) {
            int bb = idx / 25;
            int f  = idx % 25;
            const float4 v = *reinterpret_cast<const float4*>(
                x + (size_t)bb * 1000000 + (size_t)n * 1000 + chunk * 100 + f * 4);
            xs[0][bb][2*f+0] = (v.x - 0.5f) * 2.0f;
            xs[1][bb][2*f+0] = (v.y - 0.5f) * 2.0f;
            xs[0][bb][2*f+1] = (v.z - 0.5f) * 2.0f;
            xs[1][bb][2*f+1] = (v.w - 0.5f) * 2.0f;
        }
        __syncthreads();

        const float* __restrict__ wc = w1p + chunk * 50 * HID;
#pragma unroll 2
        for (int wl = 0; wl < 50; ++wl) {
            const float xv = xrow[wl];
            const float* __restrict__ wr = wc + wl * HID;
#pragma unroll
            for (int j = 0; j < 15; ++j)
                acc[j] = fmaf(xv, wr[j], acc[j]);
        }
    }

    // bias + relu + batch stats (64-lane butterfly) + normalize
#pragma unroll
    for (int j = 0; j < 15; ++j) {
        float v = acc[j] + b1[n * HID + hbase + j];
        v = fmaxf(v, 0.f);
        float s = v, ss = v * v;
#pragma unroll
        for (int off = 32; off > 0; off >>= 1) {
            s  += __shfl_xor(s, off);
            ss += __shfl_xor(ss, off);
        }
        const float mean = s * (1.f / 64.f);
        const float var  = ss * (1.f / 64.f) - mean * mean;
        const float rn   = rsqrtf(var + 1e-5f);
        hsh[lane][cbit * 32 + hbase + j] = (v - mean) * rn;
    }
    __syncthreads();

    // GEMM2: o[b,a,c] = b2[n,a] + sum_h hsh[b][c][h] * W2[n,h,a]
    const float* __restrict__ w2p = W2 + (size_t)n * (HID * ANC);
    for (int idx = t; idx < BATCH * ANC * 2; idx += 256) {
        const int b = idx / 14;
        const int r = idx % 14;
        const int a = r >> 1, c = r & 1;
        float o = b2[n * ANC + a];
        const float* hp = &hsh[b][c * 32];
#pragma unroll
        for (int h = 0; h < HID; ++h)
            o = fmaf(hp[h], w2p[h * ANC + a], o);
        out_base[(((size_t)b * ANC + a) * NWIN + n) * 2 + c] = o;
    }
}

// ---------------------------------------------------------------------------
// Kernel 2: softmax over ANC + reflect-pad + conv (only the 2 needed output
// columns) using the sum/diff factorization:
//   out0 = (S·A - D·E)/2,  out1 = (S·A + D·E)/2
//   with S,D = p[c=0] +- p[c=1];  A,E = w[kw=0] +- w[kw=1]
// grid = 64 b * 8 h-tiles (125 rows each), 256 threads.
// ---------------------------------------------------------------------------
__global__ __launch_bounds__(256, 2) void k2(
        const float* __restrict__ out_base,
        const float* __restrict__ conv_w, const float* __restrict__ conv_b,
        float* __restrict__ out_smooth)
{
    __shared__ float2 sdl[199 * ANC];       // {S,D} per (row, i)
    __shared__ float2 wael[ANC * ANC * KS]; // {A,E} per (o, i, kh)

    const int bidx = blockIdx.x;
    const int b  = bidx >> 3;
    const int ht = bidx & 7;
    const int h0 = ht * 125;
    const int t  = threadIdx.x;

    // weight transform
    const float2* __restrict__ cw2 = reinterpret_cast<const float2*>(conv_w);
    for (int idx = t; idx < ANC * ANC * KS; idx += 256) {
        const float2 w = cw2[idx];
        wael[idx] = make_float2(w.x + w.y, w.x - w.y);
    }

    // softmax rows (199 rows incl. reflect halo)
    if (t < 199) {
        const int hglob = h0 - PADH + t;
        const int hm = hglob < 0 ? -hglob
                     : (hglob >= NWIN ? 2 * NWIN - 2 - hglob : hglob);
        float p[2][ANC];
#pragma unroll
        for (int c = 0; c < 2; ++c) {
            float v[ANC];
            float m = -1e30f;
#pragma unroll
            for (int a = 0; a < ANC; ++a) {
                v[a] = out_base[(((size_t)b * ANC + a) * NWIN + hm) * 2 + c];
                m = fmaxf(m, v[a]);
            }
            float s = 0.f;
#pragma unroll
            for (int a = 0; a < ANC; ++a) { v[a] = __expf(v[a] - m); s += v[a]; }
            const float inv = 1.f / s;
#pragma unroll
            for (int a = 0; a < ANC; ++a) p[c][a] = v[a] * inv;
        }
#pragma unroll
        for (int a = 0; a < ANC; ++a)
            sdl[t * ANC + a] = make_float2(p[0][a] + p[1][a], p[0][a] - p[1][a]);
    }
    __syncthreads();

    // conv: 7 o * 125 h outputs, both output columns per thread-item
    for (int idx = t; idx < ANC * 125; idx += 256) {
        const int o  = idx / 125;
        const int hl = idx % 125;
        float sa = 0.f, de = 0.f;
        const float2* __restrict__ wrow = &wael[o * ANC * KS];
#pragma unroll 1
        for (int i = 0; i < ANC; ++i) {
            const float2* __restrict__ sdp = &sdl[hl * ANC + i];
            const float2* __restrict__ wp  = &wrow[i * KS];
#pragma unroll 5
            for (int kh = 0; kh < KS; ++kh) {
                const float2 sd = sdp[kh * ANC];
                const float2 we = wp[kh];
                sa = fmaf(sd.x, we.x, sa);
                de = fmaf(sd.y, we.y, de);
            }
        }
        const float cb = conv_b[o];
        const float o0 = 0.5f * (sa - de) + cb;
        const float o1 = 0.5f * (sa + de) + cb;
        const size_t base = (((size_t)b * ANC + o) * NWIN + (h0 + hl)) * 2;
        out_smooth[base + 0] = o0;
        out_smooth[base + 1] = o1;
    }
}

extern "C" void kernel_launch(void* const* d_in, const int* in_sizes, int n_in,
                              void* d_out, int out_size, void* d_ws, size_t ws_size,
                              hipStream_t stream)
{
    const float* x      = (const float*)d_in[0];
    const float* W1     = (const float*)d_in[1];
    const float* b1     = (const float*)d_in[2];
    const float* W2     = (const float*)d_in[3];
    const float* b2     = (const float*)d_in[4];
    const float* conv_w = (const float*)d_in[5];
    const float* conv_b = (const float*)d_in[6];
    float* out = (float*)d_out;

    k1<<<dim3(NWIN), dim3(256), 0, stream>>>(x, W1, b1, W2, b2, out);
    k2<<<dim3(BATCH * 8), dim3(256), 0, stream>>>(out, conv_w, conv_b,
                                                  out + OBASE_ELEMS);
}

// Round 2
// 211.874 us; speedup vs baseline: 1.8323x; 1.8323x over previous
//
#include <hip/hip_runtime.h>

#define NWIN 1000
#define WIN  500
#define HID  30
#define ANC  7
#define BATCH 64
#define KS   75
#define PADH 37
#define OBASE_ELEMS (BATCH*ANC*NWIN*2)   // 896000

#define CHUNK  50           // positions per chunk
#define NCHUNK 10           // 10 * 50 = 500
#define NX4    1600         // x float4s per chunk: 64 b * 25
#define NW4    375          // W1 float4s per chunk: 50*30/4

// ---------------------------------------------------------------------------
// Kernel 1: per-window  (x-0.5)*2 -> GEMM1 -> +b1 -> relu -> batchnorm over B
//           -> GEMM2 -> +b2 -> write out_base[b][a][n][c]
// grid = 1000 blocks (one per window), 256 threads = 4 waves.
// wave q: cbit = q>>1 (channel), h-half = (q&1)*15.  lane = batch.
// Both x AND W1 are staged through LDS; staging is register-prefetched and
// double-buffered against compute so HBM latency hides under the FMA chain.
// ---------------------------------------------------------------------------
__global__ __launch_bounds__(256, 3) void k1(
        const float* __restrict__ x,
        const float* __restrict__ W1, const float* __restrict__ b1,
        const float* __restrict__ W2, const float* __restrict__ b2,
        float* __restrict__ out_base)
{
    __shared__ float xs[2][CHUNK][65];   // [c][pos][batch] stride-65 -> conflict-free
    __shared__ float w1s[CHUNK][32];     // [pos][slot]: h<15 -> h, h>=15 -> h+1 (two 16-blocks)
    __shared__ float hsh[64][61];        // normalized h: [b][c*30+h]

    const int n    = blockIdx.x;
    const int t    = threadIdx.x;
    const int q    = __builtin_amdgcn_readfirstlane(t >> 6);
    const int lane = t & 63;
    const int cbit  = q >> 1;
    const int hsel  = q & 1;
    const int hbase = hsel * 15;

    // per-thread staging coordinates (constant across chunks)
    const int xb0 = t / 25,  xf0 = t % 25;          // + r*256 -> b += r*10 + carries; precompute per r
    // global bases
    const float4* __restrict__ xg = reinterpret_cast<const float4*>(x) ;
    const float4* __restrict__ wg = reinterpret_cast<const float4*>(W1 + (size_t)n * 15000);

    float4 xr[7];
    float4 wr[2];
    int xbb[7], xff[7];
#pragma unroll
    for (int r = 0; r < 7; ++r) {
        int idx = t + r * 256;
        xbb[r] = idx / 25;
        xff[r] = idx % 25;
    }

    float acc[15];
#pragma unroll
    for (int j = 0; j < 15; ++j) acc[j] = 0.f;

    const float* xrow = &xs[cbit][0][lane];
    const float4* wbase = reinterpret_cast<const float4*>(&w1s[0][hsel * 16]);

    // ---- issue loads for chunk k into regs (no use -> no wait here) ----
    auto issue = [&](int k) {
        const size_t xcbase = ((size_t)n * 1000 + (size_t)k * 100) >> 2;  // float4 units
#pragma unroll
        for (int r = 0; r < 6; ++r)
            xr[r] = xg[(size_t)xbb[r] * 250000 + xcbase + xff[r]];
        if (t < 64)   // idx = t+1536 < 1600, wave-uniform
            xr[6] = xg[(size_t)xbb[6] * 250000 + xcbase + xff[6]];
        const int wofs = k * NW4;
        wr[0] = wg[wofs + t];                    // t < 375 always (t<256)
        if (t < NW4 - 256) wr[1] = wg[wofs + t + 256];
    };

    // ---- write staged regs into LDS (waits happen here, after barrier) ----
    auto commit = [&]() {
#pragma unroll
        for (int r = 0; r < 7; ++r) {
            if (r == 6 && t >= 64) break;
            const int b = xbb[r], f = xff[r];
            const float4 v = xr[r];
            xs[0][2*f  ][b] = (v.x - 0.5f) * 2.0f;
            xs[1][2*f  ][b] = (v.y - 0.5f) * 2.0f;
            xs[0][2*f+1][b] = (v.z - 0.5f) * 2.0f;
            xs[1][2*f+1][b] = (v.w - 0.5f) * 2.0f;
        }
#pragma unroll
        for (int s = 0; s < 2; ++s) {
            const int idx = t + s * 256;
            if (s == 1 && idx >= NW4) break;
            const float4 v = s ? wr[1] : wr[0];
            const int g0 = idx * 4;
#pragma unroll
            for (int e = 0; e < 4; ++e) {
                const int g = g0 + e;
                const int w = g / 30;
                const int h = g - w * 30;
                const float val = e == 0 ? v.x : e == 1 ? v.y : e == 2 ? v.z : v.w;
                w1s[w][h + (h >= 15 ? 1 : 0)] = val;
            }
        }
    };

    issue(0);
    commit();
    __syncthreads();

    for (int k = 0; k < NCHUNK; ++k) {
        if (k + 1 < NCHUNK) issue(k + 1);

        // compute chunk k entirely from LDS
#pragma unroll 5
        for (int wl = 0; wl < CHUNK; ++wl) {
            const float xv = xrow[wl * 65];
            const float4 w0 = wbase[wl * 8 + 0];
            const float4 w1v = wbase[wl * 8 + 1];
            const float4 w2v = wbase[wl * 8 + 2];
            const float4 w3v = wbase[wl * 8 + 3];
            acc[0]  = fmaf(xv, w0.x,  acc[0]);
            acc[1]  = fmaf(xv, w0.y,  acc[1]);
            acc[2]  = fmaf(xv, w0.z,  acc[2]);
            acc[3]  = fmaf(xv, w0.w,  acc[3]);
            acc[4]  = fmaf(xv, w1v.x, acc[4]);
            acc[5]  = fmaf(xv, w1v.y, acc[5]);
            acc[6]  = fmaf(xv, w1v.z, acc[6]);
            acc[7]  = fmaf(xv, w1v.w, acc[7]);
            acc[8]  = fmaf(xv, w2v.x, acc[8]);
            acc[9]  = fmaf(xv, w2v.y, acc[9]);
            acc[10] = fmaf(xv, w2v.z, acc[10]);
            acc[11] = fmaf(xv, w2v.w, acc[11]);
            acc[12] = fmaf(xv, w3v.x, acc[12]);
            acc[13] = fmaf(xv, w3v.y, acc[13]);
            acc[14] = fmaf(xv, w3v.z, acc[14]);
        }

        __syncthreads();                 // everyone done reading buffers
        if (k + 1 < NCHUNK) {
            commit();                    // vmcnt waits land here (covered by compute)
            __syncthreads();
        }
    }

    // bias + relu + batch stats (64-lane butterfly) + normalize
#pragma unroll
    for (int j = 0; j < 15; ++j) {
        float v = acc[j] + b1[n * HID + hbase + j];
        v = fmaxf(v, 0.f);
        float s = v, ss = v * v;
#pragma unroll
        for (int off = 32; off > 0; off >>= 1) {
            s  += __shfl_xor(s, off);
            ss += __shfl_xor(ss, off);
        }
        const float mean = s * (1.f / 64.f);
        const float var  = ss * (1.f / 64.f) - mean * mean;
        const float rn   = rsqrtf(var + 1e-5f);
        hsh[lane][cbit * 30 + hbase + j] = (v - mean) * rn;
    }
    __syncthreads();

    // GEMM2: o[b,a,c] = b2[n,a] + sum_h hsh[b][c*30+h] * W2[n,h,a]
    const float* __restrict__ w2p = W2 + (size_t)n * (HID * ANC);
    for (int idx = t; idx < BATCH * ANC * 2; idx += 256) {
        const int b = idx / 14;
        const int r = idx % 14;
        const int a = r >> 1, c = r & 1;
        float o = b2[n * ANC + a];
        const float* hp = &hsh[b][c * 30];
#pragma unroll
        for (int h = 0; h < HID; ++h)
            o = fmaf(hp[h], w2p[h * ANC + a], o);
        out_base[(((size_t)b * ANC + a) * NWIN + n) * 2 + c] = o;
    }
}

// ---------------------------------------------------------------------------
// Kernel 2: softmax over ANC + reflect-pad + conv (2 needed output columns)
// via sum/diff factorization (unchanged from R0 — VALU-bound ~13us).
// ---------------------------------------------------------------------------
__global__ __launch_bounds__(256, 2) void k2(
        const float* __restrict__ out_base,
        const float* __restrict__ conv_w, const float* __restrict__ conv_b,
        float* __restrict__ out_smooth)
{
    __shared__ float2 sdl[199 * ANC];       // {S,D} per (row, i)
    __shared__ float2 wael[ANC * ANC * KS]; // {A,E} per (o, i, kh)

    const int bidx = blockIdx.x;
    const int b  = bidx >> 3;
    const int ht = bidx & 7;
    const int h0 = ht * 125;
    const int t  = threadIdx.x;

    const float2* __restrict__ cw2 = reinterpret_cast<const float2*>(conv_w);
    for (int idx = t; idx < ANC * ANC * KS; idx += 256) {
        const float2 w = cw2[idx];
        wael[idx] = make_float2(w.x + w.y, w.x - w.y);
    }

    if (t < 199) {
        const int hglob = h0 - PADH + t;
        const int hm = hglob < 0 ? -hglob
                     : (hglob >= NWIN ? 2 * NWIN - 2 - hglob : hglob);
        float p[2][ANC];
#pragma unroll
        for (int c = 0; c < 2; ++c) {
            float v[ANC];
            float m = -1e30f;
#pragma unroll
            for (int a = 0; a < ANC; ++a) {
                v[a] = out_base[(((size_t)b * ANC + a) * NWIN + hm) * 2 + c];
                m = fmaxf(m, v[a]);
            }
            float s = 0.f;
#pragma unroll
            for (int a = 0; a < ANC; ++a) { v[a] = __expf(v[a] - m); s += v[a]; }
            const float inv = 1.f / s;
#pragma unroll
            for (int a = 0; a < ANC; ++a) p[c][a] = v[a] * inv;
        }
#pragma unroll
        for (int a = 0; a < ANC; ++a)
            sdl[t * ANC + a] = make_float2(p[0][a] + p[1][a], p[0][a] - p[1][a]);
    }
    __syncthreads();

    for (int idx = t; idx < ANC * 125; idx += 256) {
        const int o  = idx / 125;
        const int hl = idx % 125;
        float sa = 0.f, de = 0.f;
        const float2* __restrict__ wrow = &wael[o * ANC * KS];
#pragma unroll 1
        for (int i = 0; i < ANC; ++i) {
            const float2* __restrict__ sdp = &sdl[hl * ANC + i];
            const float2* __restrict__ wp  = &wrow[i * KS];
#pragma unroll 5
            for (int kh = 0; kh < KS; ++kh) {
                const float2 sd = sdp[kh * ANC];
                const float2 we = wp[kh];
                sa = fmaf(sd.x, we.x, sa);
                de = fmaf(sd.y, we.y, de);
            }
        }
        const float cb = conv_b[o];
        const float o0 = 0.5f * (sa - de) + cb;
        const float o1 = 0.5f * (sa + de) + cb;
        const size_t base = (((size_t)b * ANC + o) * NWIN + (h0 + hl)) * 2;
        out_smooth[base + 0] = o0;
        out_smooth[base + 1] = o1;
    }
}

extern "C" void kernel_launch(void* const* d_in, const int* in_sizes, int n_in,
                              void* d_out, int out_size, void* d_ws, size_t ws_size,
                              hipStream_t stream)
{
    const float* x      = (const float*)d_in[0];
    const float* W1     = (const float*)d_in[1];
    const float* b1     = (const float*)d_in[2];
    const float* W2     = (const float*)d_in[3];
    const float* b2     = (const float*)d_in[4];
    const float* conv_w = (const float*)d_in[5];
    const float* conv_b = (const float*)d_in[6];
    float* out = (float*)d_out;

    k1<<<dim3(NWIN), dim3(256), 0, stream>>>(x, W1, b1, W2, b2, out);
    k2<<<dim3(BATCH * 8), dim3(256), 0, stream>>>(out, conv_w, conv_b,
                                                  out + OBASE_ELEMS);
}